// Round 1
// baseline (336.662 us; speedup 1.0000x reference)
//
#include <hip/hip_runtime.h>

// MMNL loss: loss = -mean_b( num_x[b] / (denom_x[b] * g[b]) )
//   g[b]      = sum_m alpha[m] * (has_y ? exp(z[m,b,choice]) : exp(up[m]))
//                          / (exp(up[m]) + sum_c exp(z[m,b,c]))
//   denom_x   = exp(u) + sum_c exp(x[b,c])
//   num_x     = has_y ? exp(x[b,choice]) : exp(u)
// y[b,:] is one-hot (choice < C) or all-zero (choice == C).

constexpr int Mn = 8;
constexpr int Bn = 65536;
constexpr int Cn = 100;

__global__ __launch_bounds__(256, 4) void mmnl_kernel(
    const float* __restrict__ x,
    const float* __restrict__ y,
    const float* __restrict__ z,
    const float* __restrict__ alpha,
    const float* __restrict__ u_previous,
    const float* __restrict__ u_scalar,
    float* __restrict__ out)
{
    const int lane = threadIdx.x & 63;
    const int wib  = threadIdx.x >> 6;                 // wave in block (0..3)
    const int wid  = blockIdx.x * 4 + wib;             // global wave id
    const int nw   = gridDim.x * 4;

    const float exp_u = __expf(u_scalar[0]);
    float a_m[Mn], eup[Mn];
    #pragma unroll
    for (int m = 0; m < Mn; ++m) {
        a_m[m] = alpha[m];                             // uniform scalar loads
        eup[m] = __expf(u_previous[m]);
    }

    const int  c0  = lane;
    const int  c1  = lane + 64;
    const bool hc1 = (c1 < Cn);                        // lanes 0..35 own a 2nd col

    float acc = 0.0f;

    for (int b = wid; b < Bn; b += nw) {
        // ---- issue all global loads for this customer up front (MLP) ----
        const float* xb = x + (size_t)b * Cn;
        const float* yb = y + (size_t)b * Cn;
        float xv0 = xb[c0];
        float yv0 = yb[c0];
        float xv1 = hc1 ? xb[c1] : 0.0f;
        float yv1 = hc1 ? yb[c1] : 0.0f;

        float zv0[Mn], zv1[Mn];
        #pragma unroll
        for (int m = 0; m < Mn; ++m) {
            const float* zr = z + ((size_t)m * Bn + b) * (size_t)Cn;
            zv0[m] = zr[c0];
            zv1[m] = hc1 ? zr[c1] : 0.0f;
        }

        // ---- choice detection: y is one-hot or all-zero ----
        unsigned long long b0 = __ballot(yv0 > 0.5f);
        unsigned long long b1 = __ballot(yv1 > 0.5f);
        const bool has_y = (b0 | b1) != 0ULL;
        int  src  = 0;
        bool use1 = false;
        if (b0)       { src = __ffsll(b0) - 1; }
        else if (b1)  { src = __ffsll(b1) - 1; use1 = true; }

        // ---- denom_x: wave-reduced sum of exp(x) ----
        float sex = __expf(xv0) + (hc1 ? __expf(xv1) : 0.0f);
        #pragma unroll
        for (int off = 32; off; off >>= 1)
            sex += __shfl_xor(sex, off, 64);

        // xy = x[b, choice] via single broadcast (one-hot dot)
        float xy = __shfl(use1 ? xv1 : xv0, src, 64);

        // ---- mixture term g: 8 independent reduce chains, interleaved ----
        float g = 0.0f;
        #pragma unroll
        for (int m = 0; m < Mn; ++m) {
            float sez = __expf(zv0[m]) + (hc1 ? __expf(zv1[m]) : 0.0f);
            #pragma unroll
            for (int off = 32; off; off >>= 1)
                sez += __shfl_xor(sez, off, 64);
            float zy  = __shfl(use1 ? zv1[m] : zv0[m], src, 64);
            float num = has_y ? __expf(zy) : eup[m];
            g += a_m[m] * num / (eup[m] + sez);
        }

        const float denom_x = exp_u + sex;
        const float num_x   = has_y ? __expf(xy) : exp_u;
        acc += num_x / (denom_x * g);                  // uniform across wave
    }

    // ---- block reduce (acc is wave-uniform) + one atomic per block ----
    __shared__ float bsum[4];
    if (lane == 0) bsum[wib] = acc;
    __syncthreads();
    if (threadIdx.x == 0) {
        float s = (bsum[0] + bsum[1]) + (bsum[2] + bsum[3]);
        atomicAdd(out, -s * (1.0f / (float)Bn));
    }
}

extern "C" void kernel_launch(void* const* d_in, const int* in_sizes, int n_in,
                              void* d_out, int out_size, void* d_ws, size_t ws_size,
                              hipStream_t stream) {
    const float* x  = (const float*)d_in[0];   // [B,C]
    const float* y  = (const float*)d_in[1];   // [B,C]
    const float* z  = (const float*)d_in[2];   // [M,B,C]
    const float* al = (const float*)d_in[3];   // [M]
    const float* up = (const float*)d_in[4];   // [M]
    const float* u  = (const float*)d_in[5];   // scalar

    float* out = (float*)d_out;
    // d_out is poisoned 0xAA before every call — zero it (memset node is
    // graph-capture safe), then accumulate with atomics.
    hipMemsetAsync(out, 0, sizeof(float), stream);

    dim3 grid(2048), block(256);
    mmnl_kernel<<<grid, block, 0, stream>>>(x, y, z, al, up, u, out);
}

// Round 2
// 333.128 us; speedup vs baseline: 1.0106x; 1.0106x over previous
//
#include <hip/hip_runtime.h>

// MMNL loss, restructured:
//   kernel 1: half-wave (32 lanes) per customer, float4 loads, per-block
//             partial sums -> d_ws
//   kernel 2: reduce 8192 partials -> out[0]
//
// loss = -mean_b( num_x[b] / (denom_x[b] * g[b]) )
//   g[b]    = sum_m alpha[m]*(has_y ? exp(z[m,b,ch]) : exp(up[m])) / (exp(up[m]) + sum_c exp(z[m,b,c]))
//   denom_x = exp(u) + sum_c exp(x[b,c]);  num_x = has_y ? exp(x[b,ch]) : exp(u)

constexpr int Mn = 8;
constexpr int Bn = 65536;
constexpr int Cn = 100;
constexpr int NBLK = 8192;   // 4 waves/block, 1 customer-pair per wave

__device__ __forceinline__ float sel4(float4 v, int j) {
    // j is uniform per half-wave; 3 cndmasks
    float r = (j == 1) ? v.y : v.x;
    r = (j == 2) ? v.z : r;
    r = (j == 3) ? v.w : r;
    return r;
}

__global__ __launch_bounds__(256) void mmnl_main(
    const float* __restrict__ x,
    const float* __restrict__ y,
    const float* __restrict__ z,
    const float* __restrict__ alpha,
    const float* __restrict__ up,
    const float* __restrict__ us,
    float* __restrict__ part)
{
    const int lane = threadIdx.x & 63;
    const int half = lane >> 5;            // which customer of the pair
    const int hl   = lane & 31;            // lane within half-wave
    const int wib  = threadIdx.x >> 6;
    const int wid  = blockIdx.x * 4 + wib; // pair id, 0..32767
    const bool act = (hl < 25);            // 25 float4 = 100 floats per row

    const float exp_u = __expf(us[0]);

    const int    b    = wid * 2 + half;            // customer id
    const size_t roff = (size_t)b * Cn + hl * 4;   // 16B-aligned (400%16==0)

    // ---- all global loads up front, exec-masked to the 25 active lanes ----
    float4 xv = make_float4(0.f, 0.f, 0.f, 0.f);
    float4 yv = xv;
    float4 zv[Mn];
    #pragma unroll
    for (int m = 0; m < Mn; ++m) zv[m] = xv;
    if (act) {
        xv = *(const float4*)(x + roff);
        yv = *(const float4*)(y + roff);
        #pragma unroll
        for (int m = 0; m < Mn; ++m)
            zv[m] = *(const float4*)(z + (size_t)m * ((size_t)Bn * Cn) + roff);
    }

    // ---- choice detection (y one-hot or all-zero) ----
    int loc = (yv.x > 0.5f) ? 0 : -1;
    loc = (yv.y > 0.5f) ? 1 : loc;
    loc = (yv.z > 0.5f) ? 2 : loc;
    loc = (yv.w > 0.5f) ? 3 : loc;
    const unsigned long long bal = __ballot(loc >= 0);
    const unsigned hb = (unsigned)(bal >> (half * 32));  // this half's bits
    const bool has_y = (hb != 0u);
    const int  src   = has_y ? (__ffs(hb) - 1) : 0;
    const int  srclane = half * 32 + src;
    const int  j = __shfl(loc, srclane, 64);             // element 0..3, uniform/half

    // ---- denom_x: half-wave reduced sum of exp(x) ----
    float pex = __expf(xv.x) + __expf(xv.y) + __expf(xv.z) + __expf(xv.w);
    pex = act ? pex : 0.f;                 // idle lanes would add exp(0)*4
    #pragma unroll
    for (int off = 1; off <= 16; off <<= 1) pex += __shfl_xor(pex, off, 64);
    const float xy = __shfl(sel4(xv, j), srclane, 64);

    // ---- mixture term g: 8 independent half-wave chains ----
    float g = 0.f;
    #pragma unroll
    for (int m = 0; m < Mn; ++m) {
        float pez = __expf(zv[m].x) + __expf(zv[m].y) +
                    __expf(zv[m].z) + __expf(zv[m].w);
        pez = act ? pez : 0.f;
        #pragma unroll
        for (int off = 1; off <= 16; off <<= 1) pez += __shfl_xor(pez, off, 64);
        const float zc  = __shfl(sel4(zv[m], j), srclane, 64);
        const float e   = __expf(up[m]);
        const float num = has_y ? __expf(zc) : e;
        g += (alpha[m] * num) * __builtin_amdgcn_rcpf(e + pez);
    }

    const float denom_x = exp_u + pex;
    const float num_x   = has_y ? __expf(xy) : exp_u;
    const float r       = num_x * __builtin_amdgcn_rcpf(denom_x * g);

    // ---- pair sum (r uniform per half) -> block sum -> d_ws slot ----
    const float tot = r + __shfl_xor(r, 32, 64);   // uniform across wave

    __shared__ float ls[4];
    if (lane == 0) ls[wib] = tot;
    __syncthreads();
    if (threadIdx.x == 0)
        part[blockIdx.x] = (ls[0] + ls[1]) + (ls[2] + ls[3]);
}

__global__ __launch_bounds__(256) void mmnl_reduce(
    const float* __restrict__ part, float* __restrict__ out)
{
    float s = 0.f;
    for (int i = threadIdx.x; i < NBLK; i += 256) s += part[i];
    #pragma unroll
    for (int off = 1; off <= 32; off <<= 1) s += __shfl_xor(s, off, 64);
    __shared__ float ls[4];
    const int wib = threadIdx.x >> 6;
    if ((threadIdx.x & 63) == 0) ls[wib] = s;
    __syncthreads();
    if (threadIdx.x == 0)
        out[0] = -((ls[0] + ls[1]) + (ls[2] + ls[3])) * (1.0f / (float)Bn);
}

extern "C" void kernel_launch(void* const* d_in, const int* in_sizes, int n_in,
                              void* d_out, int out_size, void* d_ws, size_t ws_size,
                              hipStream_t stream) {
    const float* x  = (const float*)d_in[0];   // [B,C]
    const float* y  = (const float*)d_in[1];   // [B,C]
    const float* z  = (const float*)d_in[2];   // [M,B,C]
    const float* al = (const float*)d_in[3];   // [M]
    const float* up = (const float*)d_in[4];   // [M]
    const float* u  = (const float*)d_in[5];   // scalar

    float* part = (float*)d_ws;                // 8192 floats, fully overwritten
    float* out  = (float*)d_out;

    mmnl_main<<<dim3(NBLK), dim3(256), 0, stream>>>(x, y, z, al, up, u, part);
    mmnl_reduce<<<dim3(1), dim3(256), 0, stream>>>(part, out);
}